// Round 1
// baseline (91.233 us; speedup 1.0000x reference)
//
#include <hip/hip_runtime.h>
#include <float.h>

constexpr int KMAX   = 11;   // KS_MAX
constexpr int SEQ    = 512;  // SEQ_LEN
constexpr int NB     = 64;   // BATCH
constexpr int LDSTR  = SEQ + 1;  // padded LDS row stride (bank spread)
constexpr int NWAVES = 8;
constexpr int BLOCK  = NWAVES * 64;

// Main per-kernel loop, specialized on tap count so weight/offset arrays are
// statically indexed (stay in VGPRs, no scratch).
template<int NJ>
__device__ __forceinline__ void main_loop(
    const float* __restrict__ xs,
    const float* __restrict__ wc_sh, const int* __restrict__ cc_sh,
    int lout, float biask, int wave, int lane, float& mx, float& cnt)
{
    float wreg[NJ];
    int   creg[NJ];
#pragma unroll
    for (int jj = 0; jj < NJ; ++jj) { wreg[jj] = wc_sh[jj]; creg[jj] = cc_sh[jj]; }

    const float* xb = xs + lane * LDSTR;   // this lane's batch row

    for (int t0 = wave * 4; t0 < lout; t0 += NWAVES * 4) {
        float a[4] = {0.f, 0.f, 0.f, 0.f};
#pragma unroll
        for (int jj = 0; jj < NJ; ++jj) {
            const int   s0 = t0 + creg[jj];    // wave-uniform
            const float wv = wreg[jj];
            if (s0 >= 0 && s0 + 3 < SEQ) {     // fast path: fully interior (uniform branch)
#pragma unroll
                for (int m = 0; m < 4; ++m)
                    a[m] = fmaf(wv, xb[s0 + m], a[m]);
            } else if (s0 > -4 && s0 < SEQ) {  // boundary chunk: per-element validity
#pragma unroll
                for (int m = 0; m < 4; ++m) {
                    int  sm  = s0 + m;
                    bool val = (sm >= 0) && (sm < SEQ);
                    int  smc = min(max(sm, 0), SEQ - 1);
                    float v  = val ? xb[smc] : 0.f;
                    a[m] = fmaf(wv, v, a[m]);
                }
            } // else fully out of range (incl. sentinel taps): contributes 0
        }
        const int rem = lout - t0;
#pragma unroll
        for (int m = 0; m < 4; ++m) {
            if (m < rem) {
                float o = a[m] + biask;
                mx  = fmaxf(mx, o);
                cnt += (o > 0.f) ? 1.f : 0.f;
            }
        }
    }
}

__global__ __launch_bounds__(BLOCK)
void rocket_fused(const float* __restrict__ x,     // [NB][SEQ] f32
                  const float* __restrict__ w,     // [K][1][KMAX] f32
                  const float* __restrict__ bias,  // [K] f32
                  const int*   __restrict__ idx,   // [K][KMAX][maxL] i32
                  const int*   __restrict__ l_out, // [K] i32
                  float*       __restrict__ out,   // [NB][2K] f32
                  int K, int maxL)
{
    __shared__ float xs[NB * LDSTR];
    __shared__ int   c_sh[KMAX];
    __shared__ float wc_sh[KMAX];
    __shared__ int   cc_sh[KMAX];
    __shared__ int   nj_sh;
    __shared__ float red_mx[NWAVES][NB];
    __shared__ float red_ct[NWAVES][NB];

    const int k    = blockIdx.x;
    const int tid  = threadIdx.x;
    const int wave = tid >> 6;
    const int lane = tid & 63;

    // ---- stage all of x into LDS, layout xs[b][LDSTR] ----
    for (int i = tid; i < NB * SEQ / 4; i += BLOCK) {
        const float4 v = reinterpret_cast<const float4*>(x)[i];
        const int flat = i * 4;
        const int b = flat >> 9;          // / SEQ
        const int s = flat & (SEQ - 1);
        float* dst = &xs[b * LDSTR + s];  // scalar writes (stride 513 unaligned for b128)
        dst[0] = v.x; dst[1] = v.y; dst[2] = v.z; dst[3] = v.w;
    }

    // ---- derive c_kj from the idx ramp: first interior value gives c = v - t ----
    for (int j = wave; j < KMAX; j += NWAVES) {
        const int* row = idx + ((size_t)k * KMAX + j) * (size_t)maxL;
        int c = 0x3FFFFFFF;               // sentinel: never valid
        for (int base = 0; base < maxL; base += 64) {
            const int t = base + lane;
            const int v = (t < maxL) ? row[t] : 0;
            const bool interior = (v > 0) && (v < SEQ - 1);   // 0 < v < 511 => v == raw
            const unsigned long long mb = __ballot(interior);
            if (mb != 0ull) {
                const int fl = __builtin_ctzll(mb);
                const int vf = __shfl(v, fl);
                c = vf - (base + fl);
                break;
            }
        }
        if (lane == 0) c_sh[j] = c;
    }
    __syncthreads();

    // ---- compact taps with nonzero weight (drops the j >= ks zero padding) ----
    if (tid == 0) {
        int n = 0;
        for (int j = 0; j < KMAX; ++j) {
            const float wj = w[(size_t)k * KMAX + j];
            if (wj != 0.0f) { wc_sh[n] = wj; cc_sh[n] = c_sh[j]; ++n; }
        }
        nj_sh = n;
        for (int jj = n; jj < KMAX; ++jj) { wc_sh[jj] = 0.f; cc_sh[jj] = 0x3FFFFFFF; }
    }
    __syncthreads();

    const int   nj    = nj_sh;
    const int   lout  = l_out[k];
    const float biask = bias[k];

    float mx = -FLT_MAX, cnt = 0.f;
    if (nj <= 7)      main_loop<7 >(xs, wc_sh, cc_sh, lout, biask, wave, lane, mx, cnt);
    else if (nj <= 9) main_loop<9 >(xs, wc_sh, cc_sh, lout, biask, wave, lane, mx, cnt);
    else              main_loop<11>(xs, wc_sh, cc_sh, lout, biask, wave, lane, mx, cnt);

    red_mx[wave][lane] = mx;
    red_ct[wave][lane] = cnt;
    __syncthreads();

    if (wave == 0) {
        float m2 = red_mx[0][lane];
        float c2 = red_ct[0][lane];
#pragma unroll
        for (int wv = 1; wv < NWAVES; ++wv) {
            m2 = fmaxf(m2, red_mx[wv][lane]);
            c2 += red_ct[wv][lane];
        }
        out[(size_t)lane * (2 * K) + 2 * k]     = m2;
        out[(size_t)lane * (2 * K) + 2 * k + 1] = c2 / (float)lout;
    }
}

extern "C" void kernel_launch(void* const* d_in, const int* in_sizes, int n_in,
                              void* d_out, int out_size, void* d_ws, size_t ws_size,
                              hipStream_t stream)
{
    const float* x    = (const float*)d_in[0];
    const float* w    = (const float*)d_in[1];
    const float* bias = (const float*)d_in[2];
    const int*   idx  = (const int*)d_in[3];
    // d_in[4] = valid  (unused: validity is derived exactly from the idx ramp)
    const int*   lout = (const int*)d_in[5];
    float* out = (float*)d_out;

    const int K    = in_sizes[2];                 // N_KERNELS (bias count)
    const int maxL = in_sizes[3] / (K * KMAX);    // idx = [K][KMAX][maxL]

    rocket_fused<<<K, BLOCK, 0, stream>>>(x, w, bias, idx, lout, out, K, maxL);
}

// Round 2
// 48.248 us; speedup vs baseline: 1.8909x; 1.8909x over previous
//
#include <hip/hip_runtime.h>
#include <float.h>

constexpr int KMAX = 11;   // KS_MAX
constexpr int SEQ  = 512;  // SEQ_LEN
constexpr int NB   = 64;   // BATCH
constexpr int NBB  = 16;   // batches per main block (4 blocks per kernel k)
constexpr int META_STRIDE = 24;   // ints per k in meta: [nj, c[11], wbits[11], pad]
constexpr int SENT = 1 << 20;     // "never valid" tap offset sentinel

// ======================= prep kernel =======================
// blocks [0, K):      derive c_kj from the idx ramp + compact nonzero-weight taps
// blocks [K, K+32):   transpose x (NBxSEQ) -> xt (SEQxNB)
__global__ __launch_bounds__(256)
void prep_kernel(const float* __restrict__ x, const float* __restrict__ w,
                 const int* __restrict__ idx, int* __restrict__ meta,
                 float* __restrict__ xt, int K, int maxL)
{
    const int tid = threadIdx.x;
    if ((int)blockIdx.x >= K) {
        // ---- transpose: coalesced f4 reads, scattered 4B writes (L2-absorbed, 131 KB) ----
        const int j  = (blockIdx.x - K) * 256 + tid;   // 0..8191
        const int b  = j >> 7;                         // 0..63
        const int s4 = j & 127;                        // 0..127
        const float4 v = reinterpret_cast<const float4*>(x)[b * 128 + s4];
        const int s0 = s4 * 4;
        xt[(s0 + 0) * NB + b] = v.x;
        xt[(s0 + 1) * NB + b] = v.y;
        xt[(s0 + 2) * NB + b] = v.z;
        xt[(s0 + 3) * NB + b] = v.w;
        return;
    }

    __shared__ int c_sh[KMAX];
    const int k    = blockIdx.x;
    const int wave = tid >> 6;
    const int lane = tid & 63;

    // idx[k,j,t] = clip(t + c, 0, 511): first interior value (0 < v < 511) gives c = v - t.
    for (int j = wave; j < KMAX; j += 4) {
        const int* row = idx + ((size_t)k * KMAX + j) * (size_t)maxL;
        int c = SENT;
        for (int base = 0; base < maxL; base += 64) {
            const int t = base + lane;
            const int v = (t < maxL) ? row[t] : 0;
            const bool interior = (v > 0) && (v < SEQ - 1);
            const unsigned long long mb = __ballot(interior);
            if (mb != 0ull) {
                const int fl = __builtin_ctzll(mb);
                const int vf = __shfl(v, fl);
                c = vf - (base + fl);
                break;
            }
        }
        if (lane == 0) c_sh[j] = c;
    }
    __syncthreads();

    if (tid == 0) {
        int* mk = meta + (size_t)k * META_STRIDE;
        int n = 0;
        for (int j = 0; j < KMAX; ++j) {
            const float wj = w[(size_t)k * KMAX + j];
            if (wj != 0.0f) {
                mk[1 + n]  = c_sh[j];
                mk[12 + n] = __float_as_int(wj);
                ++n;
            }
        }
        for (int jj = n; jj < KMAX; ++jj) { mk[1 + jj] = SENT; mk[12 + jj] = 0; }
        mk[0]  = n;
        mk[23] = 0;
    }
}

// ======================= main kernel =======================
// grid (K, 4): block = (kernel k, batch-quarter). 512 threads = 8 waves.
// lane -> (tq = lane>>2 in [0,16), bq = lane&3): lane reads float4 = 4 batches at s = t + c.
// LDS xs[s][16]: b128 banks = 16(s&1)+4bq -> 8 lanes per 4-bank group = conflict-free minimum.
template<int NJ>
__device__ __forceinline__ void conv_main(
    const float* __restrict__ xs, const int* __restrict__ msh,
    int lout, float biask, int wave, int tq, int bq,
    float (*__restrict__ red)[32])
{
    int   s[NJ];
    float wr[NJ];
#pragma unroll
    for (int j = 0; j < NJ; ++j) {
        s[j]  = wave * 16 + tq + msh[1 + j];
        wr[j] = __int_as_float(msh[12 + j]);
    }
    const char* xbase = reinterpret_cast<const char*>(xs) + bq * 16;

    float mx[4]  = {-FLT_MAX, -FLT_MAX, -FLT_MAX, -FLT_MAX};
    float cnt[4] = {0.f, 0.f, 0.f, 0.f};
    int t = wave * 16 + tq;
    const int nt = (lout + 127) >> 7;

    for (int it = 0; it < nt; ++it) {
        float a0 = 0.f, a1 = 0.f, a2 = 0.f, a3 = 0.f;
#pragma unroll
        for (int j = 0; j < NJ; ++j) {
            const int sj = s[j];
            s[j] = sj + 128;
            const unsigned sc = (unsigned)sj & 511u;               // clamp into LDS (wrong-but-masked)
            const float we = ((unsigned)sj < 512u) ? wr[j] : 0.f;  // exact validity
            const float4 v = *reinterpret_cast<const float4*>(xbase + (sc << 6));
            a0 = fmaf(we, v.x, a0);
            a1 = fmaf(we, v.y, a1);
            a2 = fmaf(we, v.z, a2);
            a3 = fmaf(we, v.w, a3);
        }
        const bool tm = (t < lout);
        t += 128;
        float o;
        o = a0 + biask; o = tm ? o : -FLT_MAX; mx[0] = fmaxf(mx[0], o); cnt[0] += (o > 0.f) ? 1.f : 0.f;
        o = a1 + biask; o = tm ? o : -FLT_MAX; mx[1] = fmaxf(mx[1], o); cnt[1] += (o > 0.f) ? 1.f : 0.f;
        o = a2 + biask; o = tm ? o : -FLT_MAX; mx[2] = fmaxf(mx[2], o); cnt[2] += (o > 0.f) ? 1.f : 0.f;
        o = a3 + biask; o = tm ? o : -FLT_MAX; mx[3] = fmaxf(mx[3], o); cnt[3] += (o > 0.f) ? 1.f : 0.f;
    }

    // reduce over tq (lane bits 2..5) via butterfly shuffles
#pragma unroll
    for (int m = 0; m < 4; ++m) {
#pragma unroll
        for (int d = 4; d <= 32; d <<= 1) {
            mx[m]  = fmaxf(mx[m], __shfl_xor(mx[m], d));
            cnt[m] += __shfl_xor(cnt[m], d);
        }
    }
    if (tq == 0) {
#pragma unroll
        for (int m = 0; m < 4; ++m) {
            red[wave][bq * 8 + m * 2 + 0] = mx[m];
            red[wave][bq * 8 + m * 2 + 1] = cnt[m];
        }
    }
}

__global__ __launch_bounds__(512)
void rocket_main(const float* __restrict__ xt, const int* __restrict__ meta,
                 const float* __restrict__ bias, const int* __restrict__ l_out,
                 float* __restrict__ out, int K)
{
    __shared__ __align__(16) float xs[SEQ * NBB];   // 32 KB: xs[s][16]
    __shared__ float red[8][32];
    __shared__ int   msh[META_STRIDE];

    const int k      = blockIdx.x;
    const int bquart = blockIdx.y;
    const int b_base = bquart * NBB;
    const int tid    = threadIdx.x;
    const int wave   = tid >> 6;
    const int lane   = tid & 63;
    const int tq     = lane >> 2;
    const int bq     = lane & 3;

    if (tid < META_STRIDE) msh[tid] = meta[(size_t)k * META_STRIDE + tid];

    // stage this block's 16 batch columns: b128 reads (coalesced) + b128 LDS writes (conflict-free)
    for (int j = tid; j < SEQ * 4; j += 512) {
        const int s  = j >> 2;
        const int bg = j & 3;
        const float4 v = reinterpret_cast<const float4*>(xt)[s * (NB / 4) + (b_base >> 2) + bg];
        *reinterpret_cast<float4*>(&xs[s * NBB + bg * 4]) = v;
    }
    __syncthreads();

    const int   nj    = msh[0];
    const int   lout  = l_out[k];
    const float biask = bias[k];

    if (nj <= 7)      conv_main<7 >(xs, msh, lout, biask, wave, tq, bq, red);
    else if (nj <= 9) conv_main<9 >(xs, msh, lout, biask, wave, tq, bq, red);
    else              conv_main<11>(xs, msh, lout, biask, wave, tq, bq, red);

    __syncthreads();

    if (tid < NBB) {   // tid = local batch; bq2 = tid>>2 (f4 group), m2 = tid&3 (elem in f4)
        const int bq2 = tid >> 2, m2 = tid & 3;
        float mxf = -FLT_MAX, ctf = 0.f;
#pragma unroll
        for (int wv = 0; wv < 8; ++wv) {
            mxf = fmaxf(mxf, red[wv][bq2 * 8 + m2 * 2 + 0]);
            ctf += red[wv][bq2 * 8 + m2 * 2 + 1];
        }
        const int b = b_base + tid;
        out[(size_t)b * (2 * K) + 2 * k]     = mxf;
        out[(size_t)b * (2 * K) + 2 * k + 1] = ctf / (float)lout;
    }
}

// ======================= launch =======================
extern "C" void kernel_launch(void* const* d_in, const int* in_sizes, int n_in,
                              void* d_out, int out_size, void* d_ws, size_t ws_size,
                              hipStream_t stream)
{
    const float* x    = (const float*)d_in[0];
    const float* w    = (const float*)d_in[1];
    const float* bias = (const float*)d_in[2];
    const int*   idx  = (const int*)d_in[3];
    // d_in[4] = valid (unused: validity derived exactly from the idx ramp)
    const int*   lout = (const int*)d_in[5];
    float* out = (float*)d_out;

    const int K    = in_sizes[2];               // N_KERNELS
    const int maxL = in_sizes[3] / (K * KMAX);  // idx = [K][KMAX][maxL]

    // workspace: meta (K*24 ints) | xt (SEQ*NB floats), 256B-aligned split (~227 KB total)
    int*   meta = (int*)d_ws;
    size_t meta_bytes = ((size_t)K * META_STRIDE * sizeof(int) + 255) & ~(size_t)255;
    float* xt = (float*)((char*)d_ws + meta_bytes);

    prep_kernel<<<K + 32, 256, 0, stream>>>(x, w, idx, meta, xt, K, maxL);
    rocket_main<<<dim3(K, 4), 512, 0, stream>>>(xt, meta, bias, lout, out, K);
}

// Round 3
// 47.083 us; speedup vs baseline: 1.9377x; 1.0248x over previous
//
#include <hip/hip_runtime.h>
#include <float.h>

constexpr int KMAX = 11;   // KS_MAX
constexpr int SEQ  = 512;  // SEQ_LEN
constexpr int NB   = 64;   // BATCH
constexpr int NBB  = 8;    // batches per main block (8 groups)
constexpr int NGRP = NB / NBB;
constexpr int META_STRIDE = 24;     // per-k meta: [nj, c[11], wbits[11], pad]
constexpr int SENT = 1 << 20;       // "never valid" tap offset sentinel
constexpr int XS_BYTES = SEQ * NBB * 4;   // 16384
constexpr int XS_MASK  = XS_BYTES - 1;

// ======================= prep kernel =======================
// blocks [0, K):    derive c_kj from the idx ramp + compact nonzero-weight taps
// blocks [K, K+32): transpose x (NB x SEQ) -> grouped xt[g][s][8]
__global__ __launch_bounds__(256)
void prep_kernel(const float* __restrict__ x, const float* __restrict__ w,
                 const int* __restrict__ idx, int* __restrict__ meta,
                 float* __restrict__ xt, int K, int maxL)
{
    const int tid = threadIdx.x;
    if ((int)blockIdx.x >= K) {
        const int j  = ((int)blockIdx.x - K) * 256 + tid;   // 0..8191
        const int b  = j >> 7;                              // 0..63
        const int s4 = j & 127;                             // 0..127
        const float4 v = reinterpret_cast<const float4*>(x)[b * (SEQ / 4) + s4];
        const int g = b >> 3, bl = b & 7;
        float* dst = xt + ((size_t)g * SEQ + s4 * 4) * NBB + bl;
        dst[0 * NBB] = v.x; dst[1 * NBB] = v.y; dst[2 * NBB] = v.z; dst[3 * NBB] = v.w;
        return;
    }

    __shared__ int c_sh[KMAX];
    const int k = blockIdx.x, wave = tid >> 6, lane = tid & 63;

    // idx[k,j,t] = clip(t + c, 0, 511): first interior value (0 < v < 511) gives c = v - t.
    for (int j = wave; j < KMAX; j += 4) {
        const int* row = idx + ((size_t)k * KMAX + j) * (size_t)maxL;
        int c = SENT;
        for (int base = 0; base < maxL; base += 64) {
            const int t = base + lane;
            const int v = (t < maxL) ? row[t] : 0;
            const bool interior = (v > 0) && (v < SEQ - 1);
            const unsigned long long mb = __ballot(interior);
            if (mb != 0ull) {
                const int fl = __builtin_ctzll(mb);
                c = __shfl(v, fl) - (base + fl);
                break;
            }
        }
        if (lane == 0) c_sh[j] = c;
    }
    __syncthreads();

    if (tid == 0) {
        int* mk = meta + (size_t)k * META_STRIDE;
        int n = 0;
        for (int j = 0; j < KMAX; ++j) {
            const float wj = w[(size_t)k * KMAX + j];
            if (wj != 0.0f) { mk[1 + n] = c_sh[j]; mk[12 + n] = __float_as_int(wj); ++n; }
        }
        for (int jj = n; jj < KMAX; ++jj) { mk[1 + jj] = SENT; mk[12 + jj] = 0; }
        mk[0]  = n;
        mk[23] = 0;
    }
}

// ======================= main kernel =======================
// grid (K, 8): block = (kernel k, batch-octet). 256 threads = 4 waves.
// lane -> (tq = lane>>1 in [0,32), bq = lane&1): lane reads float4 = 4 batches at s = t + c.
// LDS xs[s][8] (16 KB): a wave's b128 reads are 64 contiguous 16B chunks -> conflict-free.
// Per-tap LDS byte addr maintained incrementally: stride 128*32 = 4096 divides 16384,
// so (addr+4096)&16383 wraps exactly and stays in-bounds (invalid s masked via weight).
template<int NJ>
__device__ __forceinline__ void conv_main(
    const char* __restrict__ xsb, const int* __restrict__ msh,
    int lout, int off, int bq, float negb, int wave, int lane,
    float (* __restrict__ red_mx)[2][4], int (* __restrict__ red_ct)[2][4])
{
    int addr[NJ], sj[NJ]; float wr[NJ];
#pragma unroll
    for (int j = 0; j < NJ; ++j) {
        const int s0 = off + msh[1 + j];
        sj[j]   = s0;
        addr[j] = (int)(((unsigned)(s0 * 32)) & (unsigned)XS_MASK) | (bq << 4);
        wr[j]   = __int_as_float(msh[12 + j]);
    }
    float mx[4]; int ct[4];
#pragma unroll
    for (int m = 0; m < 4; ++m) { mx[m] = -FLT_MAX; ct[m] = 0; }

    const int nfull = lout >> 7;
    const int rem   = lout & 127;

    for (int it = 0; it < nfull; ++it) {
        float a[4] = {0.f, 0.f, 0.f, 0.f};
#pragma unroll
        for (int j = 0; j < NJ; ++j) {
            const float4 v = *reinterpret_cast<const float4*>(xsb + addr[j]);
            const float we = ((unsigned)sj[j] < (unsigned)SEQ) ? wr[j] : 0.f;
            sj[j]  += 128;
            addr[j] = (addr[j] + 4096) & XS_MASK;
            a[0] = fmaf(we, v.x, a[0]); a[1] = fmaf(we, v.y, a[1]);
            a[2] = fmaf(we, v.z, a[2]); a[3] = fmaf(we, v.w, a[3]);
        }
#pragma unroll
        for (int m = 0; m < 4; ++m) {
            mx[m]  = fmaxf(mx[m], a[m]);
            ct[m] += (a[m] > negb) ? 1 : 0;
        }
    }
    if (rem) {  // tail iteration: only lanes with off < rem contribute
        float a[4] = {0.f, 0.f, 0.f, 0.f};
#pragma unroll
        for (int j = 0; j < NJ; ++j) {
            const float4 v = *reinterpret_cast<const float4*>(xsb + addr[j]);
            const float we = ((unsigned)sj[j] < (unsigned)SEQ) ? wr[j] : 0.f;
            a[0] = fmaf(we, v.x, a[0]); a[1] = fmaf(we, v.y, a[1]);
            a[2] = fmaf(we, v.z, a[2]); a[3] = fmaf(we, v.w, a[3]);
        }
        const bool tm = off < rem;
#pragma unroll
        for (int m = 0; m < 4; ++m) {
            const float b = tm ? a[m] : -FLT_MAX;
            mx[m]  = fmaxf(mx[m], b);
            ct[m] += (b > negb) ? 1 : 0;
        }
    }

    // reduce over tq (lane bits 1..5)
#pragma unroll
    for (int m = 0; m < 4; ++m) {
#pragma unroll
        for (int d = 2; d <= 32; d <<= 1) {
            mx[m]  = fmaxf(mx[m], __shfl_xor(mx[m], d));
            ct[m] += __shfl_xor(ct[m], d);
        }
    }
    if ((lane >> 1) == 0) {
#pragma unroll
        for (int m = 0; m < 4; ++m) { red_mx[wave][bq][m] = mx[m]; red_ct[wave][bq][m] = ct[m]; }
    }
}

__global__ __launch_bounds__(256, 6)
void rocket_main(const float* __restrict__ xt, const int* __restrict__ meta,
                 const float* __restrict__ bias, const int* __restrict__ l_out,
                 float* __restrict__ out, int K)
{
    __shared__ __align__(16) float xs[SEQ * NBB];   // 16 KB
    __shared__ float red_mx[4][2][4];
    __shared__ int   red_ct[4][2][4];
    __shared__ int   msh[META_STRIDE];

    const int k    = blockIdx.x;
    const int grp  = blockIdx.y;
    const int tid  = threadIdx.x;
    const int wave = tid >> 6, lane = tid & 63;
    const int tq   = lane >> 1, bq = lane & 1;

    if (tid < META_STRIDE) msh[tid] = meta[(size_t)k * META_STRIDE + tid];

    // stage this group's contiguous 16 KB (coalesced f4 reads, conflict-free b128 writes)
    const float4* src = reinterpret_cast<const float4*>(xt + (size_t)grp * SEQ * NBB);
#pragma unroll
    for (int i = 0; i < (SEQ * NBB / 4) / 256; ++i)
        reinterpret_cast<float4*>(xs)[tid + i * 256] = src[tid + i * 256];
    __syncthreads();

    const int   nj    = msh[0];
    const int   lout  = l_out[k];
    const float biask = bias[k];
    const float negb  = -biask;
    const int   off   = wave * 32 + tq;   // this lane's t (mod 128)

    const char* xsb = reinterpret_cast<const char*>(xs);
    if (nj <= 7)      conv_main<7 >(xsb, msh, lout, off, bq, negb, wave, lane, red_mx, red_ct);
    else if (nj <= 9) conv_main<9 >(xsb, msh, lout, off, bq, negb, wave, lane, red_mx, red_ct);
    else              conv_main<11>(xsb, msh, lout, off, bq, negb, wave, lane, red_mx, red_ct);

    __syncthreads();

    if (tid < NBB) {   // tid = local batch = bq2*4 + m2
        const int bq2 = tid >> 2, m2 = tid & 3;
        float M = -FLT_MAX; int C = 0;
#pragma unroll
        for (int wv = 0; wv < 4; ++wv) {
            M  = fmaxf(M, red_mx[wv][bq2][m2]);
            C += red_ct[wv][bq2][m2];
        }
        const int b = grp * NBB + tid;
        out[(size_t)b * (2 * K) + 2 * k]     = M + biask;          // deferred bias
        out[(size_t)b * (2 * K) + 2 * k + 1] = (float)C / (float)lout;
    }
}

// ======================= launch =======================
extern "C" void kernel_launch(void* const* d_in, const int* in_sizes, int n_in,
                              void* d_out, int out_size, void* d_ws, size_t ws_size,
                              hipStream_t stream)
{
    const float* x    = (const float*)d_in[0];
    const float* w    = (const float*)d_in[1];
    const float* bias = (const float*)d_in[2];
    const int*   idx  = (const int*)d_in[3];
    // d_in[4] = valid (unused: validity derived exactly from the idx ramp)
    const int*   lout = (const int*)d_in[5];
    float* out = (float*)d_out;

    const int K    = in_sizes[2];               // N_KERNELS
    const int maxL = in_sizes[3] / (K * KMAX);  // idx = [K][KMAX][maxL]

    // workspace: meta (K*24 ints) | xt (SEQ*NB floats), 256B-aligned split
    int*   meta = (int*)d_ws;
    size_t meta_bytes = ((size_t)K * META_STRIDE * sizeof(int) + 255) & ~(size_t)255;
    float* xt = (float*)((char*)d_ws + meta_bytes);

    prep_kernel<<<K + 32, 256, 0, stream>>>(x, w, idx, meta, xt, K, maxL);
    rocket_main<<<dim3(K, NGRP), 256, 0, stream>>>(xt, meta, bias, lout, out, K);
}

// Round 4
// 45.961 us; speedup vs baseline: 1.9850x; 1.0244x over previous
//
#include <hip/hip_runtime.h>
#include <float.h>

constexpr int KMAX = 11;   // KS_MAX
constexpr int SEQ  = 512;  // SEQ_LEN
constexpr int NB   = 64;   // BATCH
constexpr int NBB  = 4;    // batches per main block (16 groups)
constexpr int NGRP = NB / NBB;
constexpr int META_STRIDE = 24;     // per-k meta: [nj, c[11], wbits[11], pad]
constexpr int SENT = 1 << 20;       // "never valid" tap offset sentinel
constexpr int PAD    = 64;          // zero-pad slots front
constexpr int WSLOTS = PAD + SEQ + PAD;   // 640 slots: s in [-64, 576), 16 B/slot

// ======================= prep kernel =======================
// blocks [0, K):    derive c_kj from the idx ramp + compact nonzero-weight taps
// blocks [K, K+32): transpose x (NB x SEQ) -> grouped xt[g][s][4]
__global__ __launch_bounds__(256)
void prep_kernel(const float* __restrict__ x, const float* __restrict__ w,
                 const int* __restrict__ idx, int* __restrict__ meta,
                 float* __restrict__ xt, int K, int maxL)
{
    const int tid = threadIdx.x;
    if ((int)blockIdx.x >= K) {
        const int j  = ((int)blockIdx.x - K) * 256 + tid;   // 0..8191
        const int b  = j >> 7;                              // 0..63
        const int s4 = j & 127;                             // 0..127
        const float4 v = reinterpret_cast<const float4*>(x)[b * (SEQ / 4) + s4];
        const int g = b >> 2, bl = b & 3;
        float* dst = xt + ((size_t)g * SEQ + s4 * 4) * NBB + bl;
        dst[0 * NBB] = v.x; dst[1 * NBB] = v.y; dst[2 * NBB] = v.z; dst[3 * NBB] = v.w;
        return;
    }

    __shared__ int c_sh[KMAX];
    const int k = blockIdx.x, wave = tid >> 6, lane = tid & 63;

    // idx[k,j,t] = clip(t + c, 0, 511): first interior value (0 < v < 511) gives c = v - t.
    for (int j = wave; j < KMAX; j += 4) {
        const int* row = idx + ((size_t)k * KMAX + j) * (size_t)maxL;
        int c = SENT;
        for (int base = 0; base < maxL; base += 64) {
            const int t = base + lane;
            const int v = (t < maxL) ? row[t] : 0;
            const bool interior = (v > 0) && (v < SEQ - 1);
            const unsigned long long mb = __ballot(interior);
            if (mb != 0ull) {
                const int fl = __builtin_ctzll(mb);
                c = __shfl(v, fl) - (base + fl);
                break;
            }
        }
        if (lane == 0) c_sh[j] = c;
    }
    __syncthreads();

    if (tid == 0) {
        int* mk = meta + (size_t)k * META_STRIDE;
        int n = 0;
        for (int j = 0; j < KMAX; ++j) {
            const float wj = w[(size_t)k * KMAX + j];
            if (wj != 0.0f) { mk[1 + n] = c_sh[j]; mk[12 + n] = __float_as_int(wj); ++n; }
        }
        for (int jj = n; jj < KMAX; ++jj) { mk[1 + jj] = SENT; mk[12 + jj] = 0; }
        mk[0]  = n;
        mk[23] = 0;
    }
}

// ======================= main kernel =======================
// grid (K, 16): block = (kernel k, 4-batch group). 256 threads = 4 waves.
// LDS window xs[slot][4] floats, slot = s + 64, s in [-64, 576); zeros outside [0,512)
// so out-of-range taps contribute exactly 0 (== reference's valid mask).
// Wave wv handles 64-t chunks tb = 256*i + 64*wv; lane's t = tb + lane.
// Per tap per chunk: scalar skip test (SALU, also skips the DS read), then
// 1 ds_read_b128 + 4 fma + 1 addr add. No per-element validity anywhere.
template<int NJ>
__device__ __forceinline__ void conv_body(
    const char* __restrict__ xsb, const int* __restrict__ msh,
    int lout, int wave, int lane, float negb, float (&mx)[4], int (&ct)[4])
{
    int addr[NJ]; int cs[NJ]; float wr[NJ];
#pragma unroll
    for (int j = 0; j < NJ; ++j) {
        const int c = __builtin_amdgcn_readfirstlane(msh[1 + j]);     // SGPR
        cs[j]   = c;
        wr[j]   = __int_as_float(__builtin_amdgcn_readfirstlane(msh[12 + j]));
        addr[j] = (PAD + wave * 64 + lane + c) * 16;                  // byte addr, 16 B/slot
    }
#pragma unroll
    for (int m = 0; m < 4; ++m) { mx[m] = -FLT_MAX; ct[m] = 0; }

    int tb = wave * 64;
    for (; tb + 64 <= lout; tb += 256) {   // full chunks
        float a0 = 0.f, a1 = 0.f, a2 = 0.f, a3 = 0.f;
#pragma unroll
        for (int j = 0; j < NJ; ++j) {
            if ((unsigned)(tb + cs[j] + 63) < 575u) {   // scalar: chunk touches s in [0,512)
                const float4 v = *reinterpret_cast<const float4*>(xsb + addr[j]);
                a0 = fmaf(wr[j], v.x, a0); a1 = fmaf(wr[j], v.y, a1);
                a2 = fmaf(wr[j], v.z, a2); a3 = fmaf(wr[j], v.w, a3);
            }
            addr[j] += 4096;   // 256 t * 16 B
        }
        mx[0] = fmaxf(mx[0], a0); ct[0] += (a0 > negb);
        mx[1] = fmaxf(mx[1], a1); ct[1] += (a1 > negb);
        mx[2] = fmaxf(mx[2], a2); ct[2] += (a2 > negb);
        mx[3] = fmaxf(mx[3], a3); ct[3] += (a3 > negb);
    }
    if (tb < lout) {   // straddle chunk (at most one per wave)
        float a0 = 0.f, a1 = 0.f, a2 = 0.f, a3 = 0.f;
#pragma unroll
        for (int j = 0; j < NJ; ++j) {
            if ((unsigned)(tb + cs[j] + 63) < 575u) {
                const float4 v = *reinterpret_cast<const float4*>(xsb + addr[j]);
                a0 = fmaf(wr[j], v.x, a0); a1 = fmaf(wr[j], v.y, a1);
                a2 = fmaf(wr[j], v.z, a2); a3 = fmaf(wr[j], v.w, a3);
            }
        }
        const bool tm = (tb + lane) < lout;
        a0 = tm ? a0 : -FLT_MAX; mx[0] = fmaxf(mx[0], a0); ct[0] += (a0 > negb);
        a1 = tm ? a1 : -FLT_MAX; mx[1] = fmaxf(mx[1], a1); ct[1] += (a1 > negb);
        a2 = tm ? a2 : -FLT_MAX; mx[2] = fmaxf(mx[2], a2); ct[2] += (a2 > negb);
        a3 = tm ? a3 : -FLT_MAX; mx[3] = fmaxf(mx[3], a3); ct[3] += (a3 > negb);
    }
}

__global__ __launch_bounds__(256, 6)
void rocket_main(const float* __restrict__ xt, const int* __restrict__ meta,
                 const float* __restrict__ bias, const int* __restrict__ l_out,
                 float* __restrict__ out, int K)
{
    __shared__ __align__(16) float xs[WSLOTS * NBB];   // 10240 B
    __shared__ __align__(16) float red_mx[4][64][4];   // 4 KB
    __shared__ __align__(16) float red_ct[4][64][4];   // 4 KB
    __shared__ int msh[META_STRIDE];

    const int k    = blockIdx.x;
    const int grp  = blockIdx.y;
    const int tid  = threadIdx.x;
    const int wave = __builtin_amdgcn_readfirstlane(tid >> 6);   // provably uniform -> SALU loop
    const int lane = tid & 63;

    if (tid < META_STRIDE) msh[tid] = meta[(size_t)k * META_STRIDE + tid];

    // ---- stage: zero pads (128 slots) + copy 512 real slots (all b128, conflict-free) ----
    float4* xs4 = reinterpret_cast<float4*>(xs);
    if (tid < 2 * PAD) {
        const int slot = (tid < PAD) ? tid : (tid - PAD) + PAD + SEQ;
        xs4[slot] = make_float4(0.f, 0.f, 0.f, 0.f);
    }
    const float4* src = reinterpret_cast<const float4*>(xt) + (size_t)grp * SEQ;
    xs4[PAD + tid]       = src[tid];
    xs4[PAD + 256 + tid] = src[256 + tid];
    __syncthreads();

    const int   nj    = __builtin_amdgcn_readfirstlane(msh[0]);
    const int   lout  = l_out[k];
    const float biask = bias[k];
    const float negb  = -biask;

    float mx[4]; int ct[4];
    const char* xsb = reinterpret_cast<const char*>(xs);
    if (nj <= 7)      conv_body<7 >(xsb, msh, lout, wave, lane, negb, mx, ct);
    else if (nj <= 9) conv_body<9 >(xsb, msh, lout, wave, lane, negb, mx, ct);
    else              conv_body<11>(xsb, msh, lout, wave, lane, negb, mx, ct);

    // ---- reduction: 2 b128 writes / lane, then 8 owning thread-groups finish ----
    *reinterpret_cast<float4*>(&red_mx[wave][lane][0]) = make_float4(mx[0], mx[1], mx[2], mx[3]);
    *reinterpret_cast<float4*>(&red_ct[wave][lane][0]) =
        make_float4((float)ct[0], (float)ct[1], (float)ct[2], (float)ct[3]);
    __syncthreads();

    const int sc  = tid >> 5;    // 0..3: mx for batch sc; 4..7: ct for batch sc-4
    const int p   = tid & 31;
    const int scm = sc & 3;
    if (sc < 4) {
        const float* rb = &red_mx[0][0][0];
        float v = -FLT_MAX;
#pragma unroll
        for (int wv = 0; wv < 4; ++wv) {
            v = fmaxf(v, rb[(wv * 64 + p)      * 4 + scm]);
            v = fmaxf(v, rb[(wv * 64 + p + 32) * 4 + scm]);
        }
#pragma unroll
        for (int d = 1; d <= 16; d <<= 1) v = fmaxf(v, __shfl_xor(v, d));
        if (p == 0)
            out[(size_t)(grp * NBB + scm) * (2 * K) + 2 * k] = v + biask;   // deferred bias
    } else {
        const float* rb = &red_ct[0][0][0];
        float v = 0.f;
#pragma unroll
        for (int wv = 0; wv < 4; ++wv) {
            v += rb[(wv * 64 + p)      * 4 + scm];
            v += rb[(wv * 64 + p + 32) * 4 + scm];
        }
#pragma unroll
        for (int d = 1; d <= 16; d <<= 1) v += __shfl_xor(v, d);
        if (p == 0)
            out[(size_t)(grp * NBB + scm) * (2 * K) + 2 * k + 1] = v / (float)lout;
    }
}

// ======================= launch =======================
extern "C" void kernel_launch(void* const* d_in, const int* in_sizes, int n_in,
                              void* d_out, int out_size, void* d_ws, size_t ws_size,
                              hipStream_t stream)
{
    const float* x    = (const float*)d_in[0];
    const float* w    = (const float*)d_in[1];
    const float* bias = (const float*)d_in[2];
    const int*   idx  = (const int*)d_in[3];
    // d_in[4] = valid (unused: validity derived exactly from the idx ramp)
    const int*   lout = (const int*)d_in[5];
    float* out = (float*)d_out;

    const int K    = in_sizes[2];               // N_KERNELS
    const int maxL = in_sizes[3] / (K * KMAX);  // idx = [K][KMAX][maxL]

    // workspace: meta (K*24 ints) | xt (SEQ*NB floats), 256B-aligned split
    int*   meta = (int*)d_ws;
    size_t meta_bytes = ((size_t)K * META_STRIDE * sizeof(int) + 255) & ~(size_t)255;
    float* xt = (float*)((char*)d_ws + meta_bytes);

    prep_kernel<<<K + 32, 256, 0, stream>>>(x, w, idx, meta, xt, K, maxL);
    rocket_main<<<dim3(K, NGRP), 256, 0, stream>>>(xt, meta, bias, lout, out, K);
}

// Round 6
// 42.577 us; speedup vs baseline: 2.1428x; 1.0795x over previous
//
#include <hip/hip_runtime.h>
#include <hip/hip_fp16.h>
#include <float.h>

constexpr int KMAX  = 11;    // KS_MAX
constexpr int SEQ   = 512;   // SEQ_LEN
constexpr int NB    = 64;    // BATCH
constexpr int NBB   = 8;     // batches per main block (8 groups)
constexpr int NGRP  = NB / NBB;
constexpr int MSTR  = 32;    // meta ints per k: [0]=nj [1..11]=c [12..22]=w2bits [23]=cmin [24]=cmax
constexpr int WSLOT = 1600;  // LDS window slots, 16 B (8 f16) each; slot = s - cmin

__device__ __forceinline__ unsigned h2b(__half2 h) { unsigned u; __builtin_memcpy(&u, &h, 4); return u; }
__device__ __forceinline__ __half2  b2h(unsigned u) { __half2 h; __builtin_memcpy(&h, &u, 4); return h; }

// ROCm 7.2 has no __hmax2/__hmin2 — use VOP3P directly.
__device__ __forceinline__ unsigned pkmax(unsigned a, unsigned b) {
    unsigned d; asm("v_pk_max_f16 %0, %1, %2" : "=v"(d) : "v"(a), "v"(b)); return d;
}
__device__ __forceinline__ unsigned pkmin(unsigned a, unsigned b) {
    unsigned d; asm("v_pk_min_f16 %0, %1, %2" : "=v"(d) : "v"(a), "v"(b)); return d;
}
__device__ __forceinline__ __half2 h2max(__half2 a, __half2 b) { return b2h(pkmax(h2b(a), h2b(b))); }
__device__ __forceinline__ __half2 h2min(__half2 a, __half2 b) { return b2h(pkmin(h2b(a), h2b(b))); }

// ======================= prep kernel =======================
// blocks [0, K):    derive c_kj from idx ramp, compact nonzero-weight taps (f16-packed)
// blocks [K, K+32): transpose+convert x (NB x SEQ f32) -> xt16[g][s][8] f16
__global__ __launch_bounds__(256)
void prep_kernel(const float* __restrict__ x, const float* __restrict__ w,
                 const int* __restrict__ idx, int* __restrict__ meta,
                 unsigned short* __restrict__ xt, int K, int maxL)
{
    const int tid = threadIdx.x;
    if ((int)blockIdx.x >= K) {
        const int j  = ((int)blockIdx.x - K) * 256 + tid;   // 0..8191
        const int b  = j >> 7;                              // 0..63
        const int s4 = j & 127;                             // 0..127
        const float4 v = reinterpret_cast<const float4*>(x)[b * (SEQ / 4) + s4];
        const int g = b >> 3, bl = b & 7;
        unsigned short* dst = xt + ((size_t)g * SEQ + s4 * 4) * NBB + bl;
        __half h;
        h = __float2half_rn(v.x); __builtin_memcpy(&dst[0 * NBB], &h, 2);
        h = __float2half_rn(v.y); __builtin_memcpy(&dst[1 * NBB], &h, 2);
        h = __float2half_rn(v.z); __builtin_memcpy(&dst[2 * NBB], &h, 2);
        h = __float2half_rn(v.w); __builtin_memcpy(&dst[3 * NBB], &h, 2);
        return;
    }

    __shared__ int c_sh[KMAX];
    const int k = blockIdx.x, wave = tid >> 6, lane = tid & 63;

    // idx[k,j,t] = clip(t + c, 0, 511): first interior value (0 < v < 511) gives c = v - t.
    for (int j = wave; j < KMAX; j += 4) {
        const int* row = idx + ((size_t)k * KMAX + j) * (size_t)maxL;
        int c = 0;
        for (int base = 0; base < maxL; base += 64) {
            const int t = base + lane;
            const int v = (t < maxL) ? row[t] : 0;
            const bool interior = (v > 0) && (v < SEQ - 1);
            const unsigned long long mb = __ballot(interior);
            if (mb != 0ull) {
                const int fl = __builtin_ctzll(mb);
                c = __shfl(v, fl) - (base + fl);
                break;
            }
        }
        if (lane == 0) c_sh[j] = c;
    }
    __syncthreads();

    if (tid == 0) {
        int* mk = meta + (size_t)k * MSTR;
        int n = 0, cmin = 0, cmax = 0;
        for (int j = 0; j < KMAX; ++j) {
            const float wj = w[(size_t)k * KMAX + j];
            if (wj != 0.0f) {
                const int c = c_sh[j];
                mk[1 + n] = c;
                __half hw = __float2half_rn(wj);
                unsigned short ub; __builtin_memcpy(&ub, &hw, 2);
                mk[12 + n] = (unsigned)ub | ((unsigned)ub << 16);
                cmin = min(cmin, c); cmax = max(cmax, c);
                ++n;
            }
        }
        for (int jj = n; jj < KMAX; ++jj) { mk[1 + jj] = 0; mk[12 + jj] = 0; }   // harmless pads
        mk[0]  = n;
        mk[23] = cmin;
        mk[24] = cmax;
    }
}

// ======================= main kernel =======================
// grid (K, 8): block = (kernel k, 8-batch group). 256 threads = 4 waves.
// LDS window: slot = s - cmin, 8 f16 batches per slot (16 B). Zeros outside x's
// [0,512) range => out-of-range taps contribute exactly 0 (== reference's mask).
// Branchless inner loop: all NJ ds_read_b128 issued back-to-back (deep ILP),
// packed-f16 FMAs (2 batches/instr), packed max + clamp-trick packed count.
template<int NJ>
__device__ __forceinline__ void conv_body(
    const char* __restrict__ xsc, const int* __restrict__ msh,
    int lout, int x0, int wave, int lane, __half2 cterm,
    __half2 (&mx2)[4], __half2 (&ct2)[4])
{
    const __half2 zero2 = __float2half2_rn(0.f);
    const __half2 one2  = __float2half2_rn(1.f);
    const __half2 nbig2 = __float2half2_rn(-65504.f);
    const __half2 C4    = __float2half2_rn(16384.f);   // 2^14, exact

    int addr[NJ]; __half2 wr[NJ];
#pragma unroll
    for (int j = 0; j < NJ; ++j) {
        const int c = __builtin_amdgcn_readfirstlane(msh[1 + j]);
        wr[j]   = b2h((unsigned)__builtin_amdgcn_readfirstlane(msh[12 + j]));
        addr[j] = (wave * 64 + lane + c + x0) * 16;
    }
#pragma unroll
    for (int m = 0; m < 4; ++m) { mx2[m] = nbig2; ct2[m] = zero2; }

    int tb = wave * 64;
    for (; tb + 64 <= lout; tb += 256) {
        uint4 d[NJ];
#pragma unroll
        for (int j = 0; j < NJ; ++j) {
            d[j] = *reinterpret_cast<const uint4*>(xsc + addr[j]);
            addr[j] += 4096;   // 256 t * 16 B
        }
        __half2 a[4] = {zero2, zero2, zero2, zero2};
#pragma unroll
        for (int j = 0; j < NJ; ++j) {
            a[0] = __hfma2(wr[j], b2h(d[j].x), a[0]);
            a[1] = __hfma2(wr[j], b2h(d[j].y), a[1]);
            a[2] = __hfma2(wr[j], b2h(d[j].z), a[2]);
            a[3] = __hfma2(wr[j], b2h(d[j].w), a[3]);
        }
#pragma unroll
        for (int m = 0; m < 4; ++m) {
            mx2[m] = h2max(mx2[m], a[m]);
            __half2 t = __hfma2(a[m], C4, cterm);     // (a + bias) * 2^14
            t = h2max(t, zero2); t = h2min(t, one2);
            ct2[m] = __hadd2(ct2[m], t);
        }
    }
    if (tb < lout) {   // straddle chunk: mask t >= lout via -65504 sentinel
        uint4 d[NJ];
#pragma unroll
        for (int j = 0; j < NJ; ++j) d[j] = *reinterpret_cast<const uint4*>(xsc + addr[j]);
        __half2 a[4] = {zero2, zero2, zero2, zero2};
#pragma unroll
        for (int j = 0; j < NJ; ++j) {
            a[0] = __hfma2(wr[j], b2h(d[j].x), a[0]);
            a[1] = __hfma2(wr[j], b2h(d[j].y), a[1]);
            a[2] = __hfma2(wr[j], b2h(d[j].z), a[2]);
            a[3] = __hfma2(wr[j], b2h(d[j].w), a[3]);
        }
        const bool tm = (tb + lane) < lout;
#pragma unroll
        for (int m = 0; m < 4; ++m) {
            a[m] = tm ? a[m] : nbig2;
            mx2[m] = h2max(mx2[m], a[m]);
            __half2 t = __hfma2(a[m], C4, cterm);     // -65504*2^14 -> -inf -> clamps to 0
            t = h2max(t, zero2); t = h2min(t, one2);
            ct2[m] = __hadd2(ct2[m], t);
        }
    }
}

__global__ __launch_bounds__(256, 6)
void rocket_main(const unsigned short* __restrict__ xt, const int* __restrict__ meta,
                 const float* __restrict__ bias, const int* __restrict__ l_out,
                 float* __restrict__ out, int K)
{
    __shared__ __align__(16) unsigned xs_u[WSLOT * 4];   // 25600 B window
    __shared__ unsigned redm[4][4], redc[4][4];
    __shared__ int msh[MSTR];

    const int k    = blockIdx.x;
    const int grp  = blockIdx.y;
    const int tid  = threadIdx.x;
    const int wave = __builtin_amdgcn_readfirstlane(tid >> 6);
    const int lane = tid & 63;

    if (tid < MSTR) msh[tid] = meta[(size_t)k * MSTR + tid];
    __syncthreads();

    const int   x0    = -msh[23];                   // slot of s=0 (cmin <= 0)
    const int   lout  = l_out[k];
    const float biasf = bias[k];
    const int   uend  = min(WSLOT, lout + 63 + msh[24] + x0 + 1);   // max touched slot + 1

    // ---- stage: zero only the needed pads, then copy 512 real slots (all b128) ----
    float4* xs4 = reinterpret_cast<float4*>(xs_u);
    const float4 z4 = make_float4(0.f, 0.f, 0.f, 0.f);
    for (int i = tid; i < x0; i += 256) xs4[i] = z4;
    for (int i = x0 + SEQ + tid; i < uend; i += 256) xs4[i] = z4;
    const float4* src = reinterpret_cast<const float4*>(xt + (size_t)grp * SEQ * NBB);
    xs4[x0 + tid]       = src[tid];
    xs4[x0 + 256 + tid] = src[256 + tid];
    __syncthreads();

    const int     nj    = __builtin_amdgcn_readfirstlane(msh[0]);
    const __half2 cterm = __float2half2_rn(biasf * 16384.f);

    __half2 mx2[4], ct2[4];
    const char* xsc = reinterpret_cast<const char*>(xs_u);
    if (nj <= 7)      conv_body<7 >(xsc, msh, lout, x0, wave, lane, cterm, mx2, ct2);
    else if (nj <= 9) conv_body<9 >(xsc, msh, lout, x0, wave, lane, cterm, mx2, ct2);
    else              conv_body<11>(xsc, msh, lout, x0, wave, lane, cterm, mx2, ct2);

    // ---- within-wave butterfly (packed), then 16 threads finalize ----
    unsigned um[4], uc[4];
#pragma unroll
    for (int m = 0; m < 4; ++m) { um[m] = h2b(mx2[m]); uc[m] = h2b(ct2[m]); }
#pragma unroll
    for (int dl = 1; dl <= 32; dl <<= 1) {
#pragma unroll
        for (int m = 0; m < 4; ++m) {
            um[m] = pkmax(um[m], (unsigned)__shfl_xor((int)um[m], dl));
            uc[m] = h2b(__hadd2(b2h(uc[m]), b2h((unsigned)__shfl_xor((int)uc[m], dl))));
        }
    }
    if (lane == 0) {
#pragma unroll
        for (int m = 0; m < 4; ++m) { redm[wave][m] = um[m]; redc[wave][m] = uc[m]; }
    }
    __syncthreads();

    if (tid < 16) {
        const int bl = tid >> 1, kind = tid & 1;     // batch-in-group, {max,ppv}
        const int m = bl >> 1, hi = bl & 1;
        const int b = grp * NBB + bl;
        if (kind == 0) {
            float v = -FLT_MAX;
#pragma unroll
            for (int wv = 0; wv < 4; ++wv) {
                const __half2 h = b2h(redm[wv][m]);
                v = fmaxf(v, hi ? __high2float(h) : __low2float(h));
            }
            out[(size_t)b * (2 * K) + 2 * k] = v + biasf;   // deferred bias
        } else {
            float s = 0.f;
#pragma unroll
            for (int wv = 0; wv < 4; ++wv) {
                const __half2 h = b2h(redc[wv][m]);
                s += hi ? __high2float(h) : __low2float(h);
            }
            out[(size_t)b * (2 * K) + 2 * k + 1] = s / (float)lout;
        }
    }
}

// ======================= launch =======================
extern "C" void kernel_launch(void* const* d_in, const int* in_sizes, int n_in,
                              void* d_out, int out_size, void* d_ws, size_t ws_size,
                              hipStream_t stream)
{
    const float* x    = (const float*)d_in[0];
    const float* w    = (const float*)d_in[1];
    const float* bias = (const float*)d_in[2];
    const int*   idx  = (const int*)d_in[3];
    // d_in[4] = valid (unused: validity derived exactly from the idx ramp)
    const int*   lout = (const int*)d_in[5];
    float* out = (float*)d_out;

    const int K    = in_sizes[2];               // N_KERNELS
    const int maxL = in_sizes[3] / (K * KMAX);  // idx = [K][KMAX][maxL]

    // workspace: meta (K*32 ints) | xt16 (NB*SEQ f16), 256B-aligned split
    int* meta = (int*)d_ws;
    size_t meta_bytes = ((size_t)K * MSTR * sizeof(int) + 255) & ~(size_t)255;
    unsigned short* xt = (unsigned short*)((char*)d_ws + meta_bytes);

    prep_kernel<<<K + 32, 256, 0, stream>>>(x, w, idx, meta, xt, K, maxL);
    rocket_main<<<dim3(K, NGRP), 256, 0, stream>>>(xt, meta, bias, lout, out, K);
}

// Round 7
// 35.823 us; speedup vs baseline: 2.5468x; 1.1886x over previous
//
#include <hip/hip_runtime.h>
#include <hip/hip_fp16.h>
#include <float.h>

constexpr int KMAX  = 11;    // KS_MAX
constexpr int SEQ   = 512;   // SEQ_LEN
constexpr int NB    = 64;    // BATCH
constexpr int NBB   = 8;     // batches per main block (8 groups)
constexpr int NGRP  = NB / NBB;
constexpr int MSTR  = 32;    // meta ints per k: [0]=nj [1..11]=c [12..22]=w2bits [23]=cmin [24]=cmax
constexpr int WSLOT = 1600;  // LDS window slots, 16 B (8 f16) each; slot = s - cmin

__device__ __forceinline__ unsigned h2b(__half2 h) { unsigned u; __builtin_memcpy(&u, &h, 4); return u; }
__device__ __forceinline__ __half2  b2h(unsigned u) { __half2 h; __builtin_memcpy(&h, &u, 4); return h; }

// ROCm 7.2 has no __hmax2/__hmin2 — use VOP3P directly.
__device__ __forceinline__ unsigned pkmax(unsigned a, unsigned b) {
    unsigned d; asm("v_pk_max_f16 %0, %1, %2" : "=v"(d) : "v"(a), "v"(b)); return d;
}
__device__ __forceinline__ unsigned pkmin(unsigned a, unsigned b) {
    unsigned d; asm("v_pk_min_f16 %0, %1, %2" : "=v"(d) : "v"(a), "v"(b)); return d;
}
__device__ __forceinline__ unsigned pkadd(unsigned a, unsigned b) { return h2b(__hadd2(b2h(a), b2h(b))); }
__device__ __forceinline__ __half2 h2max(__half2 a, __half2 b) { return b2h(pkmax(h2b(a), h2b(b))); }
__device__ __forceinline__ __half2 h2min(__half2 a, __half2 b) { return b2h(pkmin(h2b(a), h2b(b))); }

// DPP lane-exchange (VALU pipe, no LDS). Masked-out rows get `old` (identity).
template<int CTRL>
__device__ __forceinline__ unsigned dppmov(unsigned old, unsigned v) {
    return (unsigned)__builtin_amdgcn_update_dpp((int)old, (int)v, CTRL, 0xF, 0xF, false);
}
constexpr unsigned NEGINF2 = 0xFC00FC00u;   // -inf | -inf (f16 pair)

// Full 64-lane max reduce; result valid in lanes 48..63 (use lane 63).
__device__ __forceinline__ unsigned dpp_redmax(unsigned x) {
    x = pkmax(x, dppmov<0xB1>(NEGINF2, x));   // quad_perm(1,0,3,2)  xor1
    x = pkmax(x, dppmov<0x4E >(NEGINF2, x));  // quad_perm(2,3,0,1)  xor2
    x = pkmax(x, dppmov<0x141>(NEGINF2, x));  // row_half_mirror     xor4
    x = pkmax(x, dppmov<0x140>(NEGINF2, x));  // row_mirror          xor8
    x = pkmax(x, dppmov<0x142>(NEGINF2, x));  // row_bcast15
    x = pkmax(x, dppmov<0x143>(NEGINF2, x));  // row_bcast31
    return x;
}
// Full 64-lane sum reduce; result valid in lane 63.
__device__ __forceinline__ unsigned dpp_redadd(unsigned x) {
    x = pkadd(x, dppmov<0xB1 >(0u, x));
    x = pkadd(x, dppmov<0x4E >(0u, x));
    x = pkadd(x, dppmov<0x141>(0u, x));
    x = pkadd(x, dppmov<0x140>(0u, x));
    x = pkadd(x, dppmov<0x142>(0u, x));
    x = pkadd(x, dppmov<0x143>(0u, x));
    return x;
}

// ======================= prep kernel =======================
// blocks [0, K):    derive c_kj from idx ramp, compact nonzero-weight taps (f16-packed)
// blocks [K, K+32): transpose+convert x (NB x SEQ f32) -> xt16[g][s][8] f16
__global__ __launch_bounds__(256)
void prep_kernel(const float* __restrict__ x, const float* __restrict__ w,
                 const int* __restrict__ idx, int* __restrict__ meta,
                 unsigned short* __restrict__ xt, int K, int maxL)
{
    const int tid = threadIdx.x;
    if ((int)blockIdx.x >= K) {
        const int j  = ((int)blockIdx.x - K) * 256 + tid;   // 0..8191
        const int b  = j >> 7;                              // 0..63
        const int s4 = j & 127;                             // 0..127
        const float4 v = reinterpret_cast<const float4*>(x)[b * (SEQ / 4) + s4];
        const int g = b >> 3, bl = b & 7;
        unsigned short* dst = xt + ((size_t)g * SEQ + s4 * 4) * NBB + bl;
        __half h;
        h = __float2half_rn(v.x); __builtin_memcpy(&dst[0 * NBB], &h, 2);
        h = __float2half_rn(v.y); __builtin_memcpy(&dst[1 * NBB], &h, 2);
        h = __float2half_rn(v.z); __builtin_memcpy(&dst[2 * NBB], &h, 2);
        h = __float2half_rn(v.w); __builtin_memcpy(&dst[3 * NBB], &h, 2);
        return;
    }

    __shared__ int c_sh[KMAX];
    const int k = blockIdx.x, wave = tid >> 6, lane = tid & 63;

    // idx[k,j,t] = clip(t + c, 0, 511): first interior value (0 < v < 511) gives c = v - t.
    for (int j = wave; j < KMAX; j += 4) {
        const int* row = idx + ((size_t)k * KMAX + j) * (size_t)maxL;
        int c = 0;
        for (int base = 0; base < maxL; base += 64) {
            const int t = base + lane;
            const int v = (t < maxL) ? row[t] : 0;
            const bool interior = (v > 0) && (v < SEQ - 1);
            const unsigned long long mb = __ballot(interior);
            if (mb != 0ull) {
                const int fl = __builtin_ctzll(mb);
                c = __shfl(v, fl) - (base + fl);
                break;
            }
        }
        if (lane == 0) c_sh[j] = c;
    }
    __syncthreads();

    if (tid == 0) {
        int* mk = meta + (size_t)k * MSTR;
        int n = 0, cmin = 0, cmax = 0;
        for (int j = 0; j < KMAX; ++j) {
            const float wj = w[(size_t)k * KMAX + j];
            if (wj != 0.0f) {
                const int c = c_sh[j];
                mk[1 + n] = c;
                __half hw = __float2half_rn(wj);
                unsigned short ub; __builtin_memcpy(&ub, &hw, 2);
                mk[12 + n] = (unsigned)ub | ((unsigned)ub << 16);
                cmin = min(cmin, c); cmax = max(cmax, c);
                ++n;
            }
        }
        for (int jj = n; jj < KMAX; ++jj) { mk[1 + jj] = 0; mk[12 + jj] = 0; }   // harmless pads
        mk[0]  = n;
        mk[23] = cmin;
        mk[24] = cmax;
    }
}

// ======================= main kernel =======================
// grid (K, 8): block = (kernel k, 8-batch group). 256 threads = 4 waves.
// LDS window: slot = s - cmin, 8 f16 batches per slot (16 B). Zeros outside x's
// [0,512) range => out-of-range taps contribute exactly 0 (== reference's mask).
// Per tap per 64-t chunk: wave-uniform SALU skip test, then 1 ds_read_b128 +
// 4 packed-f16 FMAs. Cross-lane reduction entirely on the VALU pipe via DPP.
template<int NJ>
__device__ __forceinline__ void conv_body(
    const char* __restrict__ xsc, const int* __restrict__ msh,
    int lout, int x0, int wave, int lane, __half2 cterm,
    __half2 (&mx2)[4], __half2 (&ct2)[4])
{
    const __half2 zero2 = __float2half2_rn(0.f);
    const __half2 one2  = __float2half2_rn(1.f);
    const __half2 nbig2 = __float2half2_rn(-65504.f);
    const __half2 C4    = __float2half2_rn(16384.f);   // 2^14, exact

    int addr[NJ], cs[NJ]; __half2 wr[NJ];
#pragma unroll
    for (int j = 0; j < NJ; ++j) {
        cs[j]   = __builtin_amdgcn_readfirstlane(msh[1 + j]);
        wr[j]   = b2h((unsigned)__builtin_amdgcn_readfirstlane(msh[12 + j]));
        addr[j] = (wave * 64 + lane + cs[j] + x0) * 16;
    }
#pragma unroll
    for (int m = 0; m < 4; ++m) { mx2[m] = nbig2; ct2[m] = zero2; }

    int tb = wave * 64;
    for (; tb + 64 <= lout; tb += 256) {
        __half2 a[4] = {zero2, zero2, zero2, zero2};
#pragma unroll
        for (int j = 0; j < NJ; ++j) {
            if ((unsigned)(tb + cs[j] + 63) < 575u) {   // SALU: chunk touches s in [0,512)
                const uint4 d = *reinterpret_cast<const uint4*>(xsc + addr[j]);
                a[0] = __hfma2(wr[j], b2h(d.x), a[0]);
                a[1] = __hfma2(wr[j], b2h(d.y), a[1]);
                a[2] = __hfma2(wr[j], b2h(d.z), a[2]);
                a[3] = __hfma2(wr[j], b2h(d.w), a[3]);
            }
            addr[j] += 4096;   // 256 t * 16 B
        }
#pragma unroll
        for (int m = 0; m < 4; ++m) {
            mx2[m] = h2max(mx2[m], a[m]);
            __half2 t = __hfma2(a[m], C4, cterm);     // (a + bias) * 2^14
            t = h2max(t, zero2); t = h2min(t, one2);
            ct2[m] = __hadd2(ct2[m], t);
        }
    }
    if (tb < lout) {   // straddle chunk: mask t >= lout via -65504 sentinel
        __half2 a[4] = {zero2, zero2, zero2, zero2};
#pragma unroll
        for (int j = 0; j < NJ; ++j) {
            if ((unsigned)(tb + cs[j] + 63) < 575u) {
                const uint4 d = *reinterpret_cast<const uint4*>(xsc + addr[j]);
                a[0] = __hfma2(wr[j], b2h(d.x), a[0]);
                a[1] = __hfma2(wr[j], b2h(d.y), a[1]);
                a[2] = __hfma2(wr[j], b2h(d.z), a[2]);
                a[3] = __hfma2(wr[j], b2h(d.w), a[3]);
            }
        }
        const bool tm = (tb + lane) < lout;
#pragma unroll
        for (int m = 0; m < 4; ++m) {
            a[m] = tm ? a[m] : nbig2;
            mx2[m] = h2max(mx2[m], a[m]);
            __half2 t = __hfma2(a[m], C4, cterm);     // -65504*2^14 -> -inf -> clamps to 0
            t = h2max(t, zero2); t = h2min(t, one2);
            ct2[m] = __hadd2(ct2[m], t);
        }
    }
}

__global__ __launch_bounds__(256, 6)
void rocket_main(const unsigned short* __restrict__ xt, const int* __restrict__ meta,
                 const float* __restrict__ bias, const int* __restrict__ l_out,
                 float* __restrict__ out, int K)
{
    __shared__ __align__(16) unsigned xs_u[WSLOT * 4];   // 25600 B window
    __shared__ unsigned redm[4][4], redc[4][4];
    __shared__ int msh[MSTR];

    const int k    = blockIdx.x;
    const int grp  = blockIdx.y;
    const int tid  = threadIdx.x;
    const int wave = __builtin_amdgcn_readfirstlane(tid >> 6);
    const int lane = tid & 63;

    if (tid < MSTR) msh[tid] = meta[(size_t)k * MSTR + tid];
    __syncthreads();

    const int   x0    = -msh[23];                   // slot of s=0 (cmin <= 0)
    const int   lout  = l_out[k];
    const float biasf = bias[k];
    const int   uend  = min(WSLOT, lout + 63 + msh[24] + x0 + 1);   // max touched slot + 1

    // ---- stage: zero only the needed pads, then copy 512 real slots (all b128) ----
    float4* xs4 = reinterpret_cast<float4*>(xs_u);
    const float4 z4 = make_float4(0.f, 0.f, 0.f, 0.f);
    for (int i = tid; i < x0; i += 256) xs4[i] = z4;
    for (int i = x0 + SEQ + tid; i < uend; i += 256) xs4[i] = z4;
    const float4* src = reinterpret_cast<const float4*>(xt + (size_t)grp * SEQ * NBB);
    xs4[x0 + tid]       = src[tid];
    xs4[x0 + 256 + tid] = src[256 + tid];
    __syncthreads();

    const int     nj    = __builtin_amdgcn_readfirstlane(msh[0]);
    const __half2 cterm = __float2half2_rn(biasf * 16384.f);

    __half2 mx2[4], ct2[4];
    const char* xsc = reinterpret_cast<const char*>(xs_u);
    if (nj <= 7)      conv_body<7 >(xsc, msh, lout, x0, wave, lane, cterm, mx2, ct2);
    else if (nj <= 9) conv_body<9 >(xsc, msh, lout, x0, wave, lane, cterm, mx2, ct2);
    else              conv_body<11>(xsc, msh, lout, x0, wave, lane, cterm, mx2, ct2);

    // ---- 64-lane reduce on the VALU pipe (DPP); lane 63 holds the result ----
    unsigned um[4], uc[4];
#pragma unroll
    for (int m = 0; m < 4; ++m) {
        um[m] = dpp_redmax(h2b(mx2[m]));
        uc[m] = dpp_redadd(h2b(ct2[m]));
    }
    if (lane == 63) {
#pragma unroll
        for (int m = 0; m < 4; ++m) { redm[wave][m] = um[m]; redc[wave][m] = uc[m]; }
    }
    __syncthreads();

    if (tid < 16) {
        const int bl = tid >> 1, kind = tid & 1;     // batch-in-group, {max,ppv}
        const int m = bl >> 1, hi = bl & 1;
        const int b = grp * NBB + bl;
        if (kind == 0) {
            float v = -FLT_MAX;
#pragma unroll
            for (int wv = 0; wv < 4; ++wv) {
                const __half2 h = b2h(redm[wv][m]);
                v = fmaxf(v, hi ? __high2float(h) : __low2float(h));
            }
            out[(size_t)b * (2 * K) + 2 * k] = v + biasf;   // deferred bias
        } else {
            float s = 0.f;
#pragma unroll
            for (int wv = 0; wv < 4; ++wv) {
                const __half2 h = b2h(redc[wv][m]);
                s += hi ? __high2float(h) : __low2float(h);
            }
            out[(size_t)b * (2 * K) + 2 * k + 1] = s / (float)lout;
        }
    }
}

// ======================= launch =======================
extern "C" void kernel_launch(void* const* d_in, const int* in_sizes, int n_in,
                              void* d_out, int out_size, void* d_ws, size_t ws_size,
                              hipStream_t stream)
{
    const float* x    = (const float*)d_in[0];
    const float* w    = (const float*)d_in[1];
    const float* bias = (const float*)d_in[2];
    const int*   idx  = (const int*)d_in[3];
    // d_in[4] = valid (unused: validity derived exactly from the idx ramp)
    const int*   lout = (const int*)d_in[5];
    float* out = (float*)d_out;

    const int K    = in_sizes[2];               // N_KERNELS
    const int maxL = in_sizes[3] / (K * KMAX);  // idx = [K][KMAX][maxL]

    // workspace: meta (K*32 ints) | xt16 (NB*SEQ f16), 256B-aligned split
    int* meta = (int*)d_ws;
    size_t meta_bytes = ((size_t)K * MSTR * sizeof(int) + 255) & ~(size_t)255;
    unsigned short* xt = (unsigned short*)((char*)d_ws + meta_bytes);

    prep_kernel<<<K + 32, 256, 0, stream>>>(x, w, idx, meta, xt, K, maxL);
    rocket_main<<<dim3(K, NGRP), 256, 0, stream>>>(xt, meta, bias, lout, out, K);
}

// Round 8
// 33.541 us; speedup vs baseline: 2.7201x; 1.0680x over previous
//
#include <hip/hip_runtime.h>
#include <hip/hip_fp16.h>
#include <float.h>

constexpr int KMAX  = 11;    // KS_MAX
constexpr int SEQ   = 512;   // SEQ_LEN
constexpr int NB    = 64;    // BATCH
constexpr int NBB   = 8;     // batches per main block (8 groups)
constexpr int NGRP  = NB / NBB;
constexpr int MSTR  = 32;    // meta ints per k: [0]=nj [1..11]=c [12..22]=w2bits [23]=cmin [24]=cmax
constexpr int WSLOT = 1600;  // LDS window slots, 16 B (8 f16) each; slot = s - cmin
                             // span proof: lout+63+(cmax-cmin) <= 1022+63+510 = 1595 < 1600

__device__ __forceinline__ unsigned h2b(__half2 h) { unsigned u; __builtin_memcpy(&u, &h, 4); return u; }
__device__ __forceinline__ __half2  b2h(unsigned u) { __half2 h; __builtin_memcpy(&h, &u, 4); return h; }

// ROCm 7.2 has no __hmax2/__hmin2 — use VOP3P directly.
__device__ __forceinline__ unsigned pkmax(unsigned a, unsigned b) {
    unsigned d; asm("v_pk_max_f16 %0, %1, %2" : "=v"(d) : "v"(a), "v"(b)); return d;
}
__device__ __forceinline__ unsigned pkadd(unsigned a, unsigned b) { return h2b(__hadd2(b2h(a), b2h(b))); }
__device__ __forceinline__ __half2 h2max(__half2 a, __half2 b) { return b2h(pkmax(h2b(a), h2b(b))); }
// fused (a*b+c) with result clamped to [0,1] — the whole count update in one VOP3P
__device__ __forceinline__ unsigned pkfma_clamp(unsigned a, unsigned b, unsigned c) {
    unsigned d; asm("v_pk_fma_f16 %0, %1, %2, %3 clamp" : "=v"(d) : "v"(a), "v"(b), "v"(c)); return d;
}

// DPP lane-exchange (VALU pipe, no LDS). Masked-out rows get `old` (identity).
template<int CTRL>
__device__ __forceinline__ unsigned dppmov(unsigned old, unsigned v) {
    return (unsigned)__builtin_amdgcn_update_dpp((int)old, (int)v, CTRL, 0xF, 0xF, false);
}
constexpr unsigned NEGINF2 = 0xFC00FC00u;   // -inf | -inf (f16 pair)

// Full 64-lane max reduce; result valid in lane 63.
__device__ __forceinline__ unsigned dpp_redmax(unsigned x) {
    x = pkmax(x, dppmov<0xB1 >(NEGINF2, x));  // quad_perm xor1
    x = pkmax(x, dppmov<0x4E >(NEGINF2, x));  // quad_perm xor2
    x = pkmax(x, dppmov<0x141>(NEGINF2, x));  // row_half_mirror
    x = pkmax(x, dppmov<0x140>(NEGINF2, x));  // row_mirror
    x = pkmax(x, dppmov<0x142>(NEGINF2, x));  // row_bcast15
    x = pkmax(x, dppmov<0x143>(NEGINF2, x));  // row_bcast31
    return x;
}
// Full 64-lane sum reduce; result valid in lane 63.
__device__ __forceinline__ unsigned dpp_redadd(unsigned x) {
    x = pkadd(x, dppmov<0xB1 >(0u, x));
    x = pkadd(x, dppmov<0x4E >(0u, x));
    x = pkadd(x, dppmov<0x141>(0u, x));
    x = pkadd(x, dppmov<0x140>(0u, x));
    x = pkadd(x, dppmov<0x142>(0u, x));
    x = pkadd(x, dppmov<0x143>(0u, x));
    return x;
}

// ======================= prep kernel =======================
// blocks [0, K):    derive c_kj from idx ramp, compact nonzero-weight taps (f16-packed)
// blocks [K, K+32): transpose+convert x (NB x SEQ f32) -> xt16[g][s][8] f16
__global__ __launch_bounds__(256)
void prep_kernel(const float* __restrict__ x, const float* __restrict__ w,
                 const int* __restrict__ idx, int* __restrict__ meta,
                 unsigned short* __restrict__ xt, int K, int maxL)
{
    const int tid = threadIdx.x;
    if ((int)blockIdx.x >= K) {
        const int j  = ((int)blockIdx.x - K) * 256 + tid;   // 0..8191
        const int b  = j >> 7;                              // 0..63
        const int s4 = j & 127;                             // 0..127
        const float4 v = reinterpret_cast<const float4*>(x)[b * (SEQ / 4) + s4];
        const int g = b >> 3, bl = b & 7;
        unsigned short* dst = xt + ((size_t)g * SEQ + s4 * 4) * NBB + bl;
        __half h;
        h = __float2half_rn(v.x); __builtin_memcpy(&dst[0 * NBB], &h, 2);
        h = __float2half_rn(v.y); __builtin_memcpy(&dst[1 * NBB], &h, 2);
        h = __float2half_rn(v.z); __builtin_memcpy(&dst[2 * NBB], &h, 2);
        h = __float2half_rn(v.w); __builtin_memcpy(&dst[3 * NBB], &h, 2);
        return;
    }

    __shared__ int c_sh[KMAX];
    const int k = blockIdx.x, wave = tid >> 6, lane = tid & 63;

    // idx[k,j,t] = clip(t + c, 0, 511): first interior value (0 < v < 511) gives c = v - t.
    for (int j = wave; j < KMAX; j += 4) {
        const int* row = idx + ((size_t)k * KMAX + j) * (size_t)maxL;
        int c = 0;
        for (int base = 0; base < maxL; base += 64) {
            const int t = base + lane;
            const int v = (t < maxL) ? row[t] : 0;
            const bool interior = (v > 0) && (v < SEQ - 1);
            const unsigned long long mb = __ballot(interior);
            if (mb != 0ull) {
                const int fl = __builtin_ctzll(mb);
                c = __shfl(v, fl) - (base + fl);
                break;
            }
        }
        if (lane == 0) c_sh[j] = c;
    }
    __syncthreads();

    if (tid == 0) {
        int* mk = meta + (size_t)k * MSTR;
        int n = 0, cmin = 0, cmax = 0;
        for (int j = 0; j < KMAX; ++j) {
            const float wj = w[(size_t)k * KMAX + j];
            if (wj != 0.0f) {
                const int c = c_sh[j];
                mk[1 + n] = c;
                __half hw = __float2half_rn(wj);
                unsigned short ub; __builtin_memcpy(&ub, &hw, 2);
                mk[12 + n] = (unsigned)ub | ((unsigned)ub << 16);
                cmin = min(cmin, c); cmax = max(cmax, c);
                ++n;
            }
        }
        for (int jj = n; jj < KMAX; ++jj) { mk[1 + jj] = 0; mk[12 + jj] = 0; }   // harmless pads
        mk[0]  = n;
        mk[23] = cmin;
        mk[24] = cmax;
    }
}

// ======================= main kernel =======================
// grid (K, 8): block = (kernel k, 8-batch group). 256 threads = 4 waves.
// LDS window: slot = s - cmin, 8 f16 batches per slot (16 B). Zeros outside x's
// [0,512) range => out-of-range taps contribute exactly 0 (== reference's mask).
// Branchless conv: chunk ic handled by wave ic&3 at unroll-step ic>>2; all NJ
// ds_read_b128 issue back-to-back with compile-time offset immediates (it*4096).
// Count via single clamped pk_fma; cross-lane reduction on the VALU pipe (DPP).
template<int NJ>
__device__ __forceinline__ void conv_body(
    const char* __restrict__ xsc, const int* __restrict__ msh,
    int lout, int x0, int wave, int lane, unsigned ctermb,
    __half2 (&mx2)[4], __half2 (&ct2)[4])
{
    const __half2 zero2 = __float2half2_rn(0.f);
    const __half2 nbig2 = __float2half2_rn(-65504.f);
    const unsigned C4b  = 0x74007400u;   // f16 pair {2^14, 2^14}

    int addr[NJ]; __half2 wr[NJ];
#pragma unroll
    for (int j = 0; j < NJ; ++j) {
        const int c = __builtin_amdgcn_readfirstlane(msh[1 + j]);
        wr[j]   = b2h((unsigned)__builtin_amdgcn_readfirstlane(msh[12 + j]));
        addr[j] = (wave * 64 + lane + c + x0) * 16;
    }
#pragma unroll
    for (int m = 0; m < 4; ++m) { mx2[m] = nbig2; ct2[m] = zero2; }

#pragma unroll
    for (int it = 0; it < 4; ++it) {
        const int tb = wave * 64 + it * 256;
        if (tb + 64 <= lout) {             // wave-uniform SALU guard, full chunk
            uint4 d[NJ];
#pragma unroll
            for (int j = 0; j < NJ; ++j)
                d[j] = *reinterpret_cast<const uint4*>(xsc + addr[j] + it * 4096);
            __half2 a[4] = {zero2, zero2, zero2, zero2};
#pragma unroll
            for (int j = 0; j < NJ; ++j) {
                a[0] = __hfma2(wr[j], b2h(d[j].x), a[0]);
                a[1] = __hfma2(wr[j], b2h(d[j].y), a[1]);
                a[2] = __hfma2(wr[j], b2h(d[j].z), a[2]);
                a[3] = __hfma2(wr[j], b2h(d[j].w), a[3]);
            }
#pragma unroll
            for (int m = 0; m < 4; ++m) {
                mx2[m] = h2max(mx2[m], a[m]);
                ct2[m] = b2h(pkadd(h2b(ct2[m]), pkfma_clamp(h2b(a[m]), C4b, ctermb)));
            }
        }
    }

    const int rem = lout & 63;
    if (rem) {                              // partial chunk pc, owned by wave pc&3
        const int pc = lout >> 6;
        if ((pc & 3) == wave) {
            const int off = (pc >> 2) << 12;
            uint4 d[NJ];
#pragma unroll
            for (int j = 0; j < NJ; ++j)
                d[j] = *reinterpret_cast<const uint4*>(xsc + addr[j] + off);
            __half2 a[4] = {zero2, zero2, zero2, zero2};
#pragma unroll
            for (int j = 0; j < NJ; ++j) {
                a[0] = __hfma2(wr[j], b2h(d[j].x), a[0]);
                a[1] = __hfma2(wr[j], b2h(d[j].y), a[1]);
                a[2] = __hfma2(wr[j], b2h(d[j].z), a[2]);
                a[3] = __hfma2(wr[j], b2h(d[j].w), a[3]);
            }
            const bool tm = lane < rem;
#pragma unroll
            for (int m = 0; m < 4; ++m) {
                a[m] = tm ? a[m] : nbig2;   // -65504*2^14 -> -inf -> clamp -> 0
                mx2[m] = h2max(mx2[m], a[m]);
                ct2[m] = b2h(pkadd(h2b(ct2[m]), pkfma_clamp(h2b(a[m]), C4b, ctermb)));
            }
        }
    }
}

__global__ __launch_bounds__(256, 6)
void rocket_main(const unsigned short* __restrict__ xt, const int* __restrict__ meta,
                 const float* __restrict__ bias, const int* __restrict__ l_out,
                 float* __restrict__ out, int K)
{
    __shared__ __align__(16) unsigned xs_u[WSLOT * 4];   // 25600 B window
    __shared__ unsigned redm[4][4], redc[4][4];
    __shared__ int msh[MSTR];

    const int k    = blockIdx.x;
    const int grp  = blockIdx.y;
    const int tid  = threadIdx.x;
    const int wave = __builtin_amdgcn_readfirstlane(tid >> 6);
    const int lane = tid & 63;

    if (tid < MSTR) msh[tid] = meta[(size_t)k * MSTR + tid];
    __syncthreads();

    const int   x0    = -msh[23];                   // slot of s=0 (cmin <= 0)
    const int   lout  = l_out[k];
    const float biasf = bias[k];
    const int   uend  = min(WSLOT, lout + 63 + msh[24] + x0 + 1);   // max touched slot + 1

    // ---- stage: zero only the needed pads, then copy 512 real slots (all b128) ----
    float4* xs4 = reinterpret_cast<float4*>(xs_u);
    const float4 z4 = make_float4(0.f, 0.f, 0.f, 0.f);
    for (int i = tid; i < x0; i += 256) xs4[i] = z4;
    for (int i = x0 + SEQ + tid; i < uend; i += 256) xs4[i] = z4;
    const float4* src = reinterpret_cast<const float4*>(xt + (size_t)grp * SEQ * NBB);
    xs4[x0 + tid]       = src[tid];
    xs4[x0 + 256 + tid] = src[256 + tid];
    __syncthreads();

    const int      nj     = __builtin_amdgcn_readfirstlane(msh[0]);
    const unsigned ctermb = h2b(__float2half2_rn(biasf * 16384.f));

    __half2 mx2[4], ct2[4];
    const char* xsc = reinterpret_cast<const char*>(xs_u);
    if (nj <= 7)      conv_body<7 >(xsc, msh, lout, x0, wave, lane, ctermb, mx2, ct2);
    else if (nj <= 9) conv_body<9 >(xsc, msh, lout, x0, wave, lane, ctermb, mx2, ct2);
    else              conv_body<11>(xsc, msh, lout, x0, wave, lane, ctermb, mx2, ct2);

    // ---- 64-lane reduce on the VALU pipe (DPP); lane 63 holds the result ----
    unsigned um[4], uc[4];
#pragma unroll
    for (int m = 0; m < 4; ++m) {
        um[m] = dpp_redmax(h2b(mx2[m]));
        uc[m] = dpp_redadd(h2b(ct2[m]));
    }
    if (lane == 63) {
#pragma unroll
        for (int m = 0; m < 4; ++m) { redm[wave][m] = um[m]; redc[wave][m] = uc[m]; }
    }
    __syncthreads();

    if (tid < 16) {
        const int bl = tid >> 1, kind = tid & 1;     // batch-in-group, {max,ppv}
        const int m = bl >> 1, hi = bl & 1;
        const int b = grp * NBB + bl;
        if (kind == 0) {
            float v = -FLT_MAX;
#pragma unroll
            for (int wv = 0; wv < 4; ++wv) {
                const __half2 h = b2h(redm[wv][m]);
                v = fmaxf(v, hi ? __high2float(h) : __low2float(h));
            }
            out[(size_t)b * (2 * K) + 2 * k] = v + biasf;   // deferred bias
        } else {
            float s = 0.f;
#pragma unroll
            for (int wv = 0; wv < 4; ++wv) {
                const __half2 h = b2h(redc[wv][m]);
                s += hi ? __high2float(h) : __low2float(h);
            }
            out[(size_t)b * (2 * K) + 2 * k + 1] = s / (float)lout;
        }
    }
}

// ======================= launch =======================
extern "C" void kernel_launch(void* const* d_in, const int* in_sizes, int n_in,
                              void* d_out, int out_size, void* d_ws, size_t ws_size,
                              hipStream_t stream)
{
    const float* x    = (const float*)d_in[0];
    const float* w    = (const float*)d_in[1];
    const float* bias = (const float*)d_in[2];
    const int*   idx  = (const int*)d_in[3];
    // d_in[4] = valid (unused: validity derived exactly from the idx ramp)
    const int*   lout = (const int*)d_in[5];
    float* out = (float*)d_out;

    const int K    = in_sizes[2];               // N_KERNELS
    const int maxL = in_sizes[3] / (K * KMAX);  // idx = [K][KMAX][maxL]

    // workspace: meta (K*32 ints) | xt16 (NB*SEQ f16), 256B-aligned split
    int* meta = (int*)d_ws;
    size_t meta_bytes = ((size_t)K * MSTR * sizeof(int) + 255) & ~(size_t)255;
    unsigned short* xt = (unsigned short*)((char*)d_ws + meta_bytes);

    prep_kernel<<<K + 32, 256, 0, stream>>>(x, w, idx, meta, xt, K, maxL);
    rocket_main<<<dim3(K, NGRP), 256, 0, stream>>>(xt, meta, bias, lout, out, K);
}